// Round 4
// baseline (29701.129 us; speedup 1.0000x reference)
//
#include <hip/hip_runtime.h>
#include <hip/hip_bf16.h>
#include <math.h>

// Problem constants (B=8, N=1024, D=256, L=4, M=1024, H=8, dh=32, K=64 clusters)
#define BN 8192           // B*N rows
#define DMODEL 256
#define FFN 1024
#define NCLUST 64

// ---------------- Naive LayerNorm: one thread per row, two-pass (matches jnp.var) ----------------
__global__ __launch_bounds__(256) void nln(const float* __restrict__ x, const float* __restrict__ g,
                                           const float* __restrict__ b, float* __restrict__ y) {
    int row = blockIdx.x * 256 + threadIdx.x;
    if (row >= BN) return;
    const float* xr = x + (size_t)row * DMODEL;
    float m = 0.0f;
    for (int d = 0; d < DMODEL; d++) m += xr[d];
    m *= (1.0f / DMODEL);
    float v = 0.0f;
    for (int d = 0; d < DMODEL; d++) { float t = xr[d] - m; v += t * t; }
    v *= (1.0f / DMODEL);
    float rs = rsqrtf(v + 1e-5f);
    float* yr = y + (size_t)row * DMODEL;
    for (int d = 0; d < DMODEL; d++) yr[d] = (xr[d] - m) * rs * g[d] + b[d];
}

// ---------------- Naive GEMM: one thread per output element ----------------
__global__ __launch_bounds__(256) void ngemm(const float* __restrict__ A, const float* __restrict__ W,
                                             const float* __restrict__ bias, const float* __restrict__ resid,
                                             float* __restrict__ C, int M, int Nn, int K, int fuse_gelu) {
    int idx = blockIdx.x * 256 + threadIdx.x;
    if (idx >= M * Nn) return;
    int row = idx / Nn, col = idx - row * Nn;
    const float* ar = A + (size_t)row * K;
    float acc = 0.0f;
    for (int k = 0; k < K; k++) acc += ar[k] * W[(size_t)k * Nn + col];
    if (bias) acc += bias[col];
    if (fuse_gelu) acc = 0.5f * acc * (1.0f + erff(acc * 0.70710678118654752f));
    if (resid) acc += resid[idx];
    C[idx] = acc;
}

// ---------------- Naive attention: one thread per (b,h,q); two-pass softmax like reference ----------------
__global__ __launch_bounds__(256) void nattn(const float* __restrict__ q, const float* __restrict__ kv,
                                             float* __restrict__ o) {
    int idx = blockIdx.x * 256 + threadIdx.x;
    if (idx >= 8 * 8 * 1024) return;
    int h = idx & 7;
    int n = (idx >> 3) & 1023;
    int b = idx >> 13;
    const float scale = 0.17677669529663687f;  // 1/sqrt(32)
    const float* qr = q + ((size_t)(b * 1024 + n)) * DMODEL + h * 32;
    const float* kb_ = kv + (size_t)b * 1024 * 512 + h * 32;
    const float* vb_ = kb_ + 256;
    float qreg[32];
    for (int d = 0; d < 32; d++) qreg[d] = qr[d];
    // pass 1: row max
    float mx = -1e30f;
    for (int k = 0; k < 1024; k++) {
        const float* kr = kb_ + (size_t)k * 512;
        float s = 0.0f;
        for (int d = 0; d < 32; d++) s += qreg[d] * kr[d];
        s *= scale;
        mx = fmaxf(mx, s);
    }
    // pass 2: exp-sum + PV
    float acc[32];
    for (int d = 0; d < 32; d++) acc[d] = 0.0f;
    float lsum = 0.0f;
    for (int k = 0; k < 1024; k++) {
        const float* kr = kb_ + (size_t)k * 512;
        float s = 0.0f;
        for (int d = 0; d < 32; d++) s += qreg[d] * kr[d];
        s *= scale;
        float w = expf(s - mx);
        lsum += w;
        const float* vr = vb_ + (size_t)k * 512;
        for (int d = 0; d < 32; d++) acc[d] += w * vr[d];
    }
    float inv = 1.0f / lsum;
    float* orow = o + ((size_t)(b * 1024 + n)) * DMODEL + h * 32;
    for (int d = 0; d < 32; d++) orow[d] = acc[d] * inv;
}

// ---------------- K-means (naive) ----------------
__global__ __launch_bounds__(256) void km_zero(float* __restrict__ sums, float* __restrict__ counts) {
    int i = blockIdx.x * 256 + threadIdx.x;
    if (i < NCLUST * DMODEL) sums[i] = 0.0f;
    if (i < NCLUST) counts[i] = 0.0f;
}

// one thread per point; strict < gives first-min (matches jnp.argmin)
__global__ __launch_bounds__(256) void nassign(const float* __restrict__ xf, const float* __restrict__ centers,
                                               int* __restrict__ labels, float* __restrict__ counts, int do_counts) {
    int i = blockIdx.x * 256 + threadIdx.x;
    if (i >= BN) return;
    const float* xr = xf + (size_t)i * DMODEL;
    float xsq = 0.0f;
    for (int d = 0; d < DMODEL; d++) xsq += xr[d] * xr[d];
    float best = 1e30f; int bi = 0;
    for (int j = 0; j < NCLUST; j++) {
        const float* cr = centers + j * DMODEL;
        float dot = 0.0f, csq = 0.0f;
        for (int d = 0; d < DMODEL; d++) { float c = cr[d]; dot += xr[d] * c; csq += c * c; }
        float dist = xsq - 2.0f * dot + csq;
        if (dist < best) { best = dist; bi = j; }
    }
    labels[i] = bi;
    if (do_counts) atomicAdd(&counts[bi], 1.0f);
}

// one thread per point; atomic per dim
__global__ __launch_bounds__(256) void nsegsum(const float* __restrict__ xf, const int* __restrict__ labels,
                                               float* __restrict__ sums) {
    int i = blockIdx.x * 256 + threadIdx.x;
    if (i >= BN) return;
    int lab = labels[i];
    const float* xr = xf + (size_t)i * DMODEL;
    float* sr = sums + (size_t)lab * DMODEL;
    for (int d = 0; d < DMODEL; d++) atomicAdd(&sr[d], xr[d]);
}

__global__ __launch_bounds__(256) void km_update(float* __restrict__ centers, const float* __restrict__ sums,
                                                 const float* __restrict__ counts) {
    int j = blockIdx.x, d = threadIdx.x;
    float c = counts[j];
    if (c > 0.0f) centers[j * DMODEL + d] = sums[j * DMODEL + d] / fmaxf(c, 1.0f);
}

// outc[64x256] = centers @ kW + kb
__global__ __launch_bounds__(256) void nproj(const float* __restrict__ centers, const float* __restrict__ kW,
                                             const float* __restrict__ kb2, float* __restrict__ outc) {
    int idx = blockIdx.x * 256 + threadIdx.x;
    if (idx >= NCLUST * DMODEL) return;
    int row = idx >> 8, col = idx & 255;
    const float* cr = centers + row * DMODEL;
    float acc = 0.0f;
    for (int d = 0; d < DMODEL; d++) acc += cr[d] * kW[(size_t)d * DMODEL + col];
    outc[idx] = acc + kb2[col];
}

__global__ __launch_bounds__(256) void km_gather(const int* __restrict__ labels, const float* __restrict__ outc,
                                                 float* __restrict__ out) {
    int i = blockIdx.x, t = threadIdx.x;
    int lab = labels[i];
    out[(size_t)i * DMODEL + t] = outc[lab * DMODEL + t];
}

extern "C" void kernel_launch(void* const* d_in, const int* in_sizes, int n_in,
                              void* d_out, int out_size, void* d_ws, size_t ws_size,
                              hipStream_t stream) {
    const float* x_in  = (const float*)d_in[0];
    const float* ln1_g = (const float*)d_in[1];
    const float* ln1_b = (const float*)d_in[2];
    const float* Wq    = (const float*)d_in[3];
    const float* Wkv   = (const float*)d_in[4];
    const float* Wo    = (const float*)d_in[5];
    const float* bo    = (const float*)d_in[6];
    const float* ln2_g = (const float*)d_in[7];
    const float* ln2_b = (const float*)d_in[8];
    const float* W1    = (const float*)d_in[9];
    const float* b1    = (const float*)d_in[10];
    const float* W2    = (const float*)d_in[11];
    const float* b2    = (const float*)d_in[12];
    const float* kWp   = (const float*)d_in[13];
    const float* kbp   = (const float*)d_in[14];
    float* out = (float*)d_out;

    const size_t NEEDED = 42173440;
    if (ws_size < NEEDED) {
        hipMemsetAsync(d_out, 0, (size_t)out_size * sizeof(float), stream);
        return;
    }

    char* ws = (char*)d_ws;
    float* xf      = (float*)(ws);              //  8 MB   residual stream (mutable)
    float* xn      = (float*)(ws + 8388608);    //  8 MB   LN output; aliased as attention output
    float* ao      = xn;
    float* qb      = (float*)(ws + 16777216);   //  8 MB
    float* kvb     = (float*)(ws + 25165824);   // 16 MB
    float* hb      = (float*)(ws + 16777216);   // 16 MB   FFN hidden (qb/kvb dead by then)
    float* centers = (float*)(ws + 41943040);   // 64 KB
    float* sums    = (float*)(ws + 42008576);   // 64 KB
    float* counts  = (float*)(ws + 42074112);   // 1 KB region
    int*   labels  = (int*)  (ws + 42075136);   // 32 KB
    float* outc    = (float*)(ws + 42107904);   // 64 KB -> end 42173440

    hipMemcpyAsync(xf, x_in, (size_t)BN * DMODEL * sizeof(float), hipMemcpyDeviceToDevice, stream);

    for (int l = 0; l < 4; l++) {
        nln<<<32, 256, 0, stream>>>(xf, ln1_g + l * 256, ln1_b + l * 256, xn);
        ngemm<<<(BN * 256) / 256, 256, 0, stream>>>(xn, Wq + (size_t)l * 65536, nullptr, nullptr, qb, BN, 256, 256, 0);
        ngemm<<<(BN * 512) / 256, 256, 0, stream>>>(xn, Wkv + (size_t)l * 131072, nullptr, nullptr, kvb, BN, 512, 256, 0);
        nattn<<<256, 256, 0, stream>>>(qb, kvb, ao);   // ao == xn (xn dead now)
        ngemm<<<(BN * 256) / 256, 256, 0, stream>>>(ao, Wo + (size_t)l * 65536, bo + l * 256, xf, xf, BN, 256, 256, 0);
        nln<<<32, 256, 0, stream>>>(xf, ln2_g + l * 256, ln2_b + l * 256, xn);
        // FFN chunked over rows (2 x 4096) so hidden buffer fits in 16 MB (qb/kvb dead)
        for (int c = 0; c < 2; c++) {
            float* xnc = xn + (size_t)c * 4096 * 256;
            float* xfc = xf + (size_t)c * 4096 * 256;
            ngemm<<<(4096 * 1024) / 256, 256, 0, stream>>>(xnc, W1 + (size_t)l * 262144, b1 + l * 1024, nullptr, hb, 4096, 1024, 256, 1);
            ngemm<<<(4096 * 256) / 256, 256, 0, stream>>>(hb, W2 + (size_t)l * 262144, b2 + l * 256, xfc, xfc, 4096, 256, 1024, 0);
        }
    }

    hipMemcpyAsync(centers, xf, NCLUST * DMODEL * sizeof(float), hipMemcpyDeviceToDevice, stream);
    for (int it = 0; it < 10; it++) {
        km_zero<<<64, 256, 0, stream>>>(sums, counts);
        nassign<<<32, 256, 0, stream>>>(xf, centers, labels, counts, 1);
        nsegsum<<<32, 256, 0, stream>>>(xf, labels, sums);
        km_update<<<64, 256, 0, stream>>>(centers, sums, counts);
    }
    nassign<<<32, 256, 0, stream>>>(xf, centers, labels, nullptr, 0);
    nproj<<<64, 256, 0, stream>>>(centers, kWp, kbp, outc);
    km_gather<<<BN, 256, 0, stream>>>(labels, outc, out);
}

// Round 5
// 4403.911 us; speedup vs baseline: 6.7443x; 6.7443x over previous
//
#include <hip/hip_runtime.h>
#include <hip/hip_bf16.h>
#include <math.h>

// Problem constants (B=8, N=1024, D=256, L=4, M=1024, H=8, dh=32, K=64 clusters)
#define BN 8192           // B*N rows
#define DMODEL 256
#define FFN 1024
#define NCLUST 64

// ---------------- LayerNorm: one block per row, two-pass (centered variance) ----------------
__global__ __launch_bounds__(256) void ln_kernel(const float* __restrict__ x, const float* __restrict__ g,
                                                 const float* __restrict__ b, float* __restrict__ y) {
    int row = blockIdx.x, t = threadIdx.x;
    float v = x[(size_t)row * DMODEL + t];
    __shared__ float red[256];
    red[t] = v;
    __syncthreads();
    for (int off = 128; off; off >>= 1) { if (t < off) red[t] += red[t + off]; __syncthreads(); }
    float mean = red[0] * (1.0f / 256.0f);
    __syncthreads();                       // protect red[0] before reuse
    float dv = v - mean;
    red[t] = dv * dv;
    __syncthreads();
    for (int off = 128; off; off >>= 1) { if (t < off) red[t] += red[t + off]; __syncthreads(); }
    float var = red[0] * (1.0f / 256.0f);
    float rs = rsqrtf(var + 1e-5f);
    y[(size_t)row * DMODEL + t] = dv * rs * g[t] + b[t];
}

// ---------------- Tiled GEMM: C[MxN] = A[MxK] @ W[KxN] (+bias)(+gelu)(+resid), all f32 ----------------
// 64x64 tile, BK=16, 4x4 microtile; k accumulation order identical to the naive (proven) kernel.
__global__ __launch_bounds__(256) void gemm_kernel(const float* __restrict__ A, const float* __restrict__ W,
                                                   const float* __restrict__ bias, const float* __restrict__ resid,
                                                   float* __restrict__ C, int M, int Nn, int K, int fuse_gelu) {
    __shared__ float As[64][17];
    __shared__ float Bs[16][64];
    int t = threadIdx.x;
    int tx = t & 15, ty = t >> 4;
    int m0 = blockIdx.y * 64, n0 = blockIdx.x * 64;
    float acc[4][4] = {};
    for (int k0 = 0; k0 < K; k0 += 16) {
        {
            int mrow = t >> 2, kq = (t & 3) * 4;
            const float4 a4 = *reinterpret_cast<const float4*>(A + (size_t)(m0 + mrow) * K + k0 + kq);
            As[mrow][kq] = a4.x; As[mrow][kq + 1] = a4.y; As[mrow][kq + 2] = a4.z; As[mrow][kq + 3] = a4.w;
        }
        {
            int kk = t >> 4, c4 = (t & 15) * 4;
            const float4 b4 = *reinterpret_cast<const float4*>(W + (size_t)(k0 + kk) * Nn + n0 + c4);
            Bs[kk][c4] = b4.x; Bs[kk][c4 + 1] = b4.y; Bs[kk][c4 + 2] = b4.z; Bs[kk][c4 + 3] = b4.w;
        }
        __syncthreads();
#pragma unroll
        for (int kk = 0; kk < 16; kk++) {
            float a[4], b[4];
#pragma unroll
            for (int i = 0; i < 4; i++) a[i] = As[ty * 4 + i][kk];
#pragma unroll
            for (int j = 0; j < 4; j++) b[j] = Bs[kk][tx * 4 + j];
#pragma unroll
            for (int i = 0; i < 4; i++)
#pragma unroll
                for (int j = 0; j < 4; j++) acc[i][j] += a[i] * b[j];
        }
        __syncthreads();
    }
#pragma unroll
    for (int i = 0; i < 4; i++) {
#pragma unroll
        for (int j = 0; j < 4; j++) {
            int row = m0 + ty * 4 + i, col = n0 + tx * 4 + j;
            float v = acc[i][j];
            if (bias) v += bias[col];
            if (fuse_gelu) v = 0.5f * v * (1.0f + erff(v * 0.70710678118654752f));
            if (resid) v += resid[(size_t)row * Nn + col];
            C[(size_t)row * Nn + col] = v;
        }
    }
}

// ---------------- Two-pass attention: one wave per q-row, 4 rows per block ----------------
// Numerics mirror the naive kernel: exact max, identical exp args, k-ascending PV per dim.
__global__ __launch_bounds__(256) void attn2(const float* __restrict__ q, const float* __restrict__ kv,
                                             float* __restrict__ o) {
    int bh = blockIdx.x, b = bh >> 3, h = bh & 7;
    int qg = blockIdx.y;                 // 4 q-rows per block
    int t = threadIdx.x, w = t >> 6, l = t & 63;
    int n = qg * 4 + w;
    __shared__ float KVs[64][33];        // K tile (pass 1) then V tile (pass 2); pad -> conflict-free
    __shared__ float S[4][1024];         // per-wave score row
    const float scale = 0.17677669529663687f;  // 1/sqrt(32)
    const float* kbase = kv + (size_t)b * 1024 * 512 + h * 32;
    const float* vbase = kbase + 256;
    const float* qrow = q + ((size_t)(b * 1024 + n)) * DMODEL + h * 32;
    float qreg[32];
#pragma unroll
    for (int d = 0; d < 32; d++) qreg[d] = qrow[d];

    // pass 1: scores + max
    float mx = -1e30f;
    for (int kt = 0; kt < 16; kt++) {
        __syncthreads();
#pragma unroll
        for (int i = 0; i < 8; i++) {
            int idx = t * 8 + i; int kr = idx >> 5, d = idx & 31;
            KVs[kr][d] = kbase[(size_t)(kt * 64 + kr) * 512 + d];
        }
        __syncthreads();
        float s = 0.0f;
#pragma unroll
        for (int d = 0; d < 32; d++) s += qreg[d] * KVs[l][d];
        s *= scale;
        S[w][kt * 64 + l] = s;
        mx = fmaxf(mx, s);
    }
    for (int off = 1; off < 64; off <<= 1) mx = fmaxf(mx, __shfl_xor(mx, off));

    // weights + row sum (S row owned by this wave; lane l owns k = kt*64+l)
    float lsum = 0.0f;
#pragma unroll
    for (int kt = 0; kt < 16; kt++) {
        float e = expf(S[w][kt * 64 + l] - mx);
        S[w][kt * 64 + l] = e;
        lsum += e;
    }
    for (int off = 1; off < 64; off <<= 1) lsum += __shfl_xor(lsum, off);
    float inv = 1.0f / lsum;

    // pass 2: O_d = sum_k w_k * V[k][d], k ascending (lanes 0..31 own dims)
    float od = 0.0f;
    int d = l & 31;
    for (int kt = 0; kt < 16; kt++) {
        __syncthreads();
#pragma unroll
        for (int i = 0; i < 8; i++) {
            int idx = t * 8 + i; int kr = idx >> 5, dd = idx & 31;
            KVs[kr][dd] = vbase[(size_t)(kt * 64 + kr) * 512 + dd];
        }
        __syncthreads();
        if (l < 32) {
            for (int c = 0; c < 64; c++) od += S[w][kt * 64 + c] * KVs[c][d];
        }
    }
    if (l < 32) o[((size_t)(b * 1024 + n)) * DMODEL + h * 32 + d] = od * inv;
}

// ---------------- K-means ----------------
__global__ __launch_bounds__(256) void km_zero(float* __restrict__ sums, float* __restrict__ counts) {
    int i = blockIdx.x * 256 + threadIdx.x;
    if (i < NCLUST * DMODEL) sums[i] = 0.0f;
    if (i < NCLUST) counts[i] = 0.0f;
}

// lane-per-center; distances bit-identical to naive (same d-ascending fma chains).
// 512 blocks x 16 points; centers staged transposed in LDS (padded stride 65: conflict-free).
__global__ __launch_bounds__(256) void km_assign(const float* __restrict__ xf, const float* __restrict__ centers,
                                                 int* __restrict__ labels, float* __restrict__ counts, int do_counts) {
    __shared__ float CsT[DMODEL][NCLUST + 1];
    int t = threadIdx.x;
    for (int i = 0; i < 64; i++) CsT[t][i] = centers[i * DMODEL + t];
    __syncthreads();
    int lane = t & 63, wv = t >> 6;
    float csq = 0.0f;
    for (int d = 0; d < DMODEL; d++) { float c = CsT[d][lane]; csq += c * c; }
    for (int p = 0; p < 4; p++) {
        int i = blockIdx.x * 16 + wv * 4 + p;
        const float* xr = xf + (size_t)i * DMODEL;
        float dot = 0.0f, xsq = 0.0f;
        for (int d = 0; d < DMODEL; d++) { float xv = xr[d]; dot += xv * CsT[d][lane]; xsq += xv * xv; }
        float dist = xsq - 2.0f * dot + csq;
        float best = dist; int bi = lane;
        for (int off = 1; off < 64; off <<= 1) {
            float ov = __shfl_xor(best, off);
            int oi = __shfl_xor(bi, off);
            if (ov < best || (ov == best && oi < bi)) { best = ov; bi = oi; }
        }
        if (lane == 0) {
            labels[i] = bi;
            if (do_counts) atomicAdd(&counts[bi], 1.0f);
        }
    }
}

// thread t owns dim-column t across all centers (race-free); 128 points/block, one atomic flush
__global__ __launch_bounds__(256) void km_segsum(const float* __restrict__ xf, const int* __restrict__ labels,
                                                 float* __restrict__ sums) {
    __shared__ float lsum[NCLUST][DMODEL];
    int t = threadIdx.x;
    for (int j = 0; j < NCLUST; j++) lsum[j][t] = 0.0f;
    int base = blockIdx.x * 128;
    for (int p = 0; p < 128; p++) {
        int i = base + p;
        int lab = labels[i];
        lsum[lab][t] += xf[(size_t)i * DMODEL + t];
    }
    for (int j = 0; j < NCLUST; j++) atomicAdd(&sums[j * DMODEL + t], lsum[j][t]);
}

__global__ __launch_bounds__(256) void km_update(float* __restrict__ centers, const float* __restrict__ sums,
                                                 const float* __restrict__ counts) {
    int j = blockIdx.x, d = threadIdx.x;
    float c = counts[j];
    if (c > 0.0f) centers[j * DMODEL + d] = sums[j * DMODEL + d] / fmaxf(c, 1.0f);
}

// outc[64x256] = centers @ kW + kb
__global__ __launch_bounds__(256) void nproj(const float* __restrict__ centers, const float* __restrict__ kW,
                                             const float* __restrict__ kb2, float* __restrict__ outc) {
    int idx = blockIdx.x * 256 + threadIdx.x;
    if (idx >= NCLUST * DMODEL) return;
    int row = idx >> 8, col = idx & 255;
    const float* cr = centers + row * DMODEL;
    float acc = 0.0f;
    for (int d = 0; d < DMODEL; d++) acc += cr[d] * kW[(size_t)d * DMODEL + col];
    outc[idx] = acc + kb2[col];
}

__global__ __launch_bounds__(256) void km_gather(const int* __restrict__ labels, const float* __restrict__ outc,
                                                 float* __restrict__ out) {
    int i = blockIdx.x, t = threadIdx.x;
    int lab = labels[i];
    out[(size_t)i * DMODEL + t] = outc[lab * DMODEL + t];
}

extern "C" void kernel_launch(void* const* d_in, const int* in_sizes, int n_in,
                              void* d_out, int out_size, void* d_ws, size_t ws_size,
                              hipStream_t stream) {
    const float* x_in  = (const float*)d_in[0];
    const float* ln1_g = (const float*)d_in[1];
    const float* ln1_b = (const float*)d_in[2];
    const float* Wq    = (const float*)d_in[3];
    const float* Wkv   = (const float*)d_in[4];
    const float* Wo    = (const float*)d_in[5];
    const float* bo    = (const float*)d_in[6];
    const float* ln2_g = (const float*)d_in[7];
    const float* ln2_b = (const float*)d_in[8];
    const float* W1    = (const float*)d_in[9];
    const float* b1    = (const float*)d_in[10];
    const float* W2    = (const float*)d_in[11];
    const float* b2    = (const float*)d_in[12];
    const float* kWp   = (const float*)d_in[13];
    const float* kbp   = (const float*)d_in[14];
    float* out = (float*)d_out;

    const size_t NEEDED = 42173440;
    if (ws_size < NEEDED) {
        hipMemsetAsync(d_out, 0, (size_t)out_size * sizeof(float), stream);
        return;
    }

    char* ws = (char*)d_ws;
    float* xf      = (float*)(ws);              //  8 MB   residual stream (mutable)
    float* xn      = (float*)(ws + 8388608);    //  8 MB   LN output; aliased as attention output
    float* ao      = xn;
    float* qb      = (float*)(ws + 16777216);   //  8 MB
    float* kvb     = (float*)(ws + 25165824);   // 16 MB
    float* hb      = (float*)(ws + 16777216);   // 16 MB   FFN hidden (qb/kvb dead by then)
    float* centers = (float*)(ws + 41943040);   // 64 KB
    float* sums    = (float*)(ws + 42008576);   // 64 KB
    float* counts  = (float*)(ws + 42074112);   // 1 KB region
    int*   labels  = (int*)  (ws + 42075136);   // 32 KB
    float* outc    = (float*)(ws + 42107904);   // 64 KB -> end 42173440

    hipMemcpyAsync(xf, x_in, (size_t)BN * DMODEL * sizeof(float), hipMemcpyDeviceToDevice, stream);

    for (int l = 0; l < 4; l++) {
        ln_kernel<<<BN, 256, 0, stream>>>(xf, ln1_g + l * 256, ln1_b + l * 256, xn);
        gemm_kernel<<<dim3(4, 128), 256, 0, stream>>>(xn, Wq + (size_t)l * 65536, nullptr, nullptr, qb, BN, 256, 256, 0);
        gemm_kernel<<<dim3(8, 128), 256, 0, stream>>>(xn, Wkv + (size_t)l * 131072, nullptr, nullptr, kvb, BN, 512, 256, 0);
        attn2<<<dim3(64, 256), 256, 0, stream>>>(qb, kvb, ao);   // ao == xn (xn dead now)
        gemm_kernel<<<dim3(4, 128), 256, 0, stream>>>(ao, Wo + (size_t)l * 65536, bo + l * 256, xf, xf, BN, 256, 256, 0);
        ln_kernel<<<BN, 256, 0, stream>>>(xf, ln2_g + l * 256, ln2_b + l * 256, xn);
        // FFN chunked over rows (2 x 4096) so hidden buffer fits in 16 MB (qb/kvb dead)
        for (int c = 0; c < 2; c++) {
            float* xnc = xn + (size_t)c * 4096 * 256;
            float* xfc = xf + (size_t)c * 4096 * 256;
            gemm_kernel<<<dim3(16, 64), 256, 0, stream>>>(xnc, W1 + (size_t)l * 262144, b1 + l * 1024, nullptr, hb, 4096, 1024, 256, 1);
            gemm_kernel<<<dim3(4, 64), 256, 0, stream>>>(hb, W2 + (size_t)l * 262144, b2 + l * 256, xfc, xfc, 4096, 256, 1024, 0);
        }
    }

    hipMemcpyAsync(centers, xf, NCLUST * DMODEL * sizeof(float), hipMemcpyDeviceToDevice, stream);
    for (int it = 0; it < 10; it++) {
        km_zero<<<64, 256, 0, stream>>>(sums, counts);
        km_assign<<<512, 256, 0, stream>>>(xf, centers, labels, counts, 1);
        km_segsum<<<64, 256, 0, stream>>>(xf, labels, sums);
        km_update<<<64, 256, 0, stream>>>(centers, sums, counts);
    }
    km_assign<<<512, 256, 0, stream>>>(xf, centers, labels, nullptr, 0);
    nproj<<<64, 256, 0, stream>>>(centers, kWp, kbp, outc);
    km_gather<<<BN, 256, 0, stream>>>(labels, outc, out);
}